// Round 5
// baseline (467.952 us; speedup 1.0000x reference)
//
#include <hip/hip_runtime.h>
#include <hip/hip_fp16.h>

#define B_ 256
#define T_ 200
#define H_ 256
#define G3 768            // 3*H
#define NV 50001          // V+1
#define RQ 20             // rec: uint4 groups (4 K-pairs each) in registers
#define LQ 12             // rec: uint4 groups persistent in LDS (RQ+LQ=32)

typedef _Float16 half2v __attribute__((ext_vector_type(2)));
typedef _Float16 half4v __attribute__((ext_vector_type(4)));
typedef _Float16 half8v __attribute__((ext_vector_type(8)));
typedef float f32x4 __attribute__((ext_vector_type(4)));

union U32H2 { unsigned int u; half2v h; };

__device__ __forceinline__ float fdot2(half2v a, half2v b, float c) {
  return __builtin_amdgcn_fdot2(a, b, c, false);
}
__device__ __forceinline__ float sigmoidf_(float x) {
  return 1.f / (1.f + __expf(-x));
}
__device__ __forceinline__ float tanhf_(float x) {
  float ax = fabsf(x);
  float e = __expf(-2.f * ax);
  float t = (1.f - e) / (1.f + e);
  return copysignf(t, x);
}
__device__ __forceinline__ f32x4 mfma16(half8v a, half8v b, f32x4 c) {
  return __builtin_amdgcn_mfma_f32_16x16x32_f16(a, b, c, 0, 0, 0);
}
__device__ __forceinline__ float dot4u(uint4 w, uint4 h, float a0, float a1,
                                       float* o1) {
  U32H2 w0, w1, w2, w3, c0, c1, c2, c3;
  w0.u = w.x; w1.u = w.y; w2.u = w.z; w3.u = w.w;
  c0.u = h.x; c1.u = h.y; c2.u = h.z; c3.u = h.w;
  a0 = fdot2(w0.h, c0.h, a0);
  a1 = fdot2(w1.h, c1.h, a1);
  a0 = fdot2(w2.h, c2.h, a0);
  a1 = fdot2(w3.h, c3.h, a1);
  *o1 = a1;
  return a0;
}

// ---- pack w_hh [256][768] fp32 -> q-major K-pair fp16:
// out[(q*768 + col)*4 + j] = (w[2(4q+j)][col], w[2(4q+j)+1][col]),
// q in [0,32). Thread tid's uint4 group q sits at element (q*768+tid):
// contiguous 16B, coalesced across lanes.
__global__ __launch_bounds__(256) void pack_whh_r(
    const float* __restrict__ whh, unsigned int* __restrict__ out) {
  int idx = blockIdx.x * 256 + threadIdx.x;   // 0..98303
  int j = idx & 3;
  int e = idx >> 2;
  int q = e / G3;
  int col = e - q * G3;
  int k = 2 * (4 * q + j);
  U32H2 u;
  u.h.x = (_Float16)whh[(size_t)k * G3 + col];
  u.h.y = (_Float16)whh[(size_t)(k + 1) * G3 + col];
  out[idx] = u.u;
}

// ---- pack w_ih -> transposed fp16 [768 cols][256 k] (gates_mfma B staging).
__global__ __launch_bounds__(256) void pack_wiht(
    const float* __restrict__ wih, unsigned int* __restrict__ out) {
  int idx = blockIdx.x * 256 + threadIdx.x;   // 0..98303
  int col = idx >> 7;
  int kk = (idx & 127) * 2;
  U32H2 u;
  u.h.x = (_Float16)wih[(size_t)kk * G3 + col];
  u.h.y = (_Float16)wih[(size_t)(kk + 1) * G3 + col];
  out[idx] = u.u;
}

// ---- K1: gates = emb[ids] @ w_ih + b_ih via f16 MFMA (round-2, measured).
__global__ __launch_bounds__(512) void gates_mfma(
    const int* __restrict__ ids, const float* __restrict__ emb,
    const __half* __restrict__ wih_t, const float* __restrict__ b_ih,
    __half* __restrict__ gates) {
  __shared__ __align__(16) _Float16 As[128 * 72];   // [row][k] stride 72
  __shared__ __align__(16) _Float16 Bs[256 * 72];   // [col][k] stride 72
  __shared__ int ids_s[128];
  __shared__ float bs[256];
  const int tid = threadIdx.x;
  const int r0 = blockIdx.x * 128;
  const int c0 = blockIdx.y * 256;
  const int w = tid >> 6, lane = tid & 63;
  const int wm = w >> 2, wn = w & 3;
  const int lr = lane & 15, lk = lane >> 4;

  if (tid < 128) ids_s[tid] = ids[r0 + tid];
  if (tid < 256) bs[tid] = b_ih[c0 + tid];
  __syncthreads();

  f32x4 acc[4][4];
#pragma unroll
  for (int i = 0; i < 4; ++i)
#pragma unroll
    for (int j = 0; j < 4; ++j) acc[i][j] = (f32x4){0.f, 0.f, 0.f, 0.f};

  for (int c = 0; c < 4; ++c) {
    const int kc = c * 64;
#pragma unroll
    for (int r4 = 0; r4 < 4; ++r4) {
      int q = tid + r4 * 512;
      int row = q >> 4;
      int kk = (q & 15) * 4;
      const float4 v = *(const float4*)&emb[(size_t)ids_s[row] * H_ + kc + kk];
      half4v hv = {(_Float16)v.x, (_Float16)v.y, (_Float16)v.z, (_Float16)v.w};
      *(half4v*)&As[row * 72 + kk] = hv;
    }
#pragma unroll
    for (int r4 = 0; r4 < 4; ++r4) {
      int q = tid + r4 * 512;
      int col = q >> 3;
      int cc = q & 7;
      uint4 v = *(const uint4*)((const unsigned short*)wih_t +
                                (size_t)(c0 + col) * H_ + kc + cc * 8);
      *(uint4*)&Bs[col * 72 + cc * 8] = v;
    }
    __syncthreads();
#pragma unroll
    for (int ks = 0; ks < 2; ++ks) {
      half8v af[4], bf[4];
#pragma unroll
      for (int i = 0; i < 4; ++i)
        af[i] = *(const half8v*)&As[(wm * 64 + i * 16 + lr) * 72 + ks * 32 + lk * 8];
#pragma unroll
      for (int j = 0; j < 4; ++j)
        bf[j] = *(const half8v*)&Bs[(wn * 64 + j * 16 + lr) * 72 + ks * 32 + lk * 8];
#pragma unroll
      for (int i = 0; i < 4; ++i)
#pragma unroll
        for (int j = 0; j < 4; ++j)
          acc[i][j] = mfma16(af[i], bf[j], acc[i][j]);
    }
    __syncthreads();
  }
#pragma unroll
  for (int j = 0; j < 4; ++j) {
    const int col = c0 + wn * 64 + j * 16 + lr;
    const float bj = bs[wn * 64 + j * 16 + lr];
#pragma unroll
    for (int i = 0; i < 4; ++i) {
      const int row = r0 + wm * 64 + i * 16 + lk * 4;
#pragma unroll
      for (int r = 0; r < 4; ++r)
        gates[(size_t)(row + r) * G3 + col] = (__half)(acc[i][j][r] + bj);
    }
  }
}

// ---- K2: GRU recurrence, 256 WGs x 768 thr.
// Weight delivery: 80 K-pairs pinned in VGPRs via opaque inline-asm loads
// (compiler cannot rematerialize), 48 K-pairs persistent in LDS (conflict-
// free b128). waves_per_eu(3,3) pins the VGPR cap at 168 so the allocator
// keeps the 80 weight regs instead of targeting 6-wave occupancy (the
// round-0/4 failure: cap 80 -> remat -> full per-step L2 re-stream).
__global__ __launch_bounds__(768, 3) __attribute__((amdgpu_waves_per_eu(3, 3)))
void rec_kernel(const int* __restrict__ lens,
                const unsigned int* __restrict__ whh_r,
                const float* __restrict__ b_hh, const __half* __restrict__ gates,
                float* __restrict__ hfin) {
  __shared__ float rec[G3];
  __shared__ __align__(16) __half hpk[256];
  __shared__ uint4 Wl4[LQ * G3];   // 147,456 B: q groups 20..31
  const int tid = threadIdx.x;
  const int b = blockIdx.x;

  // q groups 0..19 -> 80 VGPRs, loaded opaquely
  const uint4* wr = (const uint4*)whh_r + tid;
  uint4 Wv[RQ];
#pragma unroll
  for (int q = 0; q < RQ; ++q) {
    asm volatile("global_load_dwordx4 %0, %1, off"
                 : "=v"(Wv[q])
                 : "v"(wr + (size_t)q * G3));
  }
  asm volatile("s_waitcnt vmcnt(0)" ::: "memory");
  __builtin_amdgcn_sched_barrier(0);

  // q groups 20..31 -> LDS
#pragma unroll
  for (int q = 0; q < LQ; ++q)
    Wl4[q * G3 + tid] = wr[(size_t)(RQ + q) * G3];

  const int len = lens[b];
  float bh0 = 0.f, bh1 = 0.f, bh2 = 0.f;
  float h = 0.f;
  if (tid < 256) {
    bh0 = b_hh[tid];
    bh1 = b_hh[256 + tid];
    bh2 = b_hh[512 + tid];
    hpk[tid] = (__half)0.f;
  }
  __syncthreads();

  const uint4* hx = (const uint4*)&hpk[0];
  const __half* gp = gates + (size_t)b * T_ * G3 + tid;
  for (int t = 0; t < len; ++t) {
    float gxz = 0.f, gxr = 0.f, gxh = 0.f;
    if (tid < 256) {  // prefetch; consumed after the barrier
      const __half* gpt = gp + (size_t)t * G3;
      gxz = (float)gpt[0];
      gxr = (float)gpt[256];
      gxh = (float)gpt[512];
    }
    float a0 = 0.f, a1 = 0.f;
#pragma unroll
    for (int q = 0; q < RQ; ++q)
      a0 = dot4u(Wv[q], hx[q], a0, a1, &a1);
#pragma unroll
    for (int q = 0; q < LQ; ++q) {
      uint4 wv = Wl4[q * G3 + tid];
      a0 = dot4u(wv, hx[RQ + q], a0, a1, &a1);
    }
    rec[tid] = a0 + a1;
    __syncthreads();
    if (tid < 256) {
      float z = sigmoidf_(gxz + rec[tid] + bh0);
      float r = sigmoidf_(gxr + rec[256 + tid] + bh1);
      float hh = tanhf_(gxh + r * (rec[512 + tid] + bh2));
      h = z * h + (1.f - z) * hh;
      hpk[tid] = (__half)h;
    }
    __syncthreads();
  }
  if (tid < 256) hfin[(size_t)b * H_ + tid] = h;
}

// ---- K3: logits = hfin @ emb^T via hi/lo-split f16 MFMA (round-2, measured).
__global__ __launch_bounds__(512) void logits_mfma(
    const float* __restrict__ hfin, const float* __restrict__ emb,
    float* __restrict__ out) {
  __shared__ __align__(16) _Float16 As[256 * 72];
  __shared__ __align__(16) _Float16 Bs[64 * 72];
  const int tid = threadIdx.x;
  const int n0 = blockIdx.x * 64;
  const int w = tid >> 6, lane = tid & 63;
  const int wm = w >> 1, wn = w & 1;
  const int lr = lane & 15, lk = lane >> 4;

  f32x4 a1[4][2], a2[4][2];
#pragma unroll
  for (int i = 0; i < 4; ++i)
#pragma unroll
    for (int j = 0; j < 2; ++j) {
      a1[i][j] = (f32x4){0.f, 0.f, 0.f, 0.f};
      a2[i][j] = (f32x4){0.f, 0.f, 0.f, 0.f};
    }

  for (int c = 0; c < 8; ++c) {
    const int kc = c * 32;
#pragma unroll
    for (int r4 = 0; r4 < 4; ++r4) {
      int q = tid + r4 * 512;
      int row = q >> 3;
      int kk = (q & 7) * 4;
      float4 v = *(const float4*)&hfin[(size_t)row * H_ + kc + kk];
      half4v hi = {(_Float16)v.x, (_Float16)v.y, (_Float16)v.z, (_Float16)v.w};
      half4v lo = {(_Float16)((v.x - (float)hi.x) * 1024.f),
                   (_Float16)((v.y - (float)hi.y) * 1024.f),
                   (_Float16)((v.z - (float)hi.z) * 1024.f),
                   (_Float16)((v.w - (float)hi.w) * 1024.f)};
      int base = row * 72 + (kk >> 3) * 16 + (kk & 7);
      *(half4v*)&As[base] = hi;
      *(half4v*)&As[base + 8] = lo;
    }
    {
      int col = tid >> 3;
      int kk = (tid & 7) * 4;
      int n = n0 + col;
      float4 v = (n < NV) ? *(const float4*)&emb[(size_t)n * H_ + kc + kk]
                          : make_float4(0.f, 0.f, 0.f, 0.f);
      half4v hi = {(_Float16)v.x, (_Float16)v.y, (_Float16)v.z, (_Float16)v.w};
      half4v lo = {(_Float16)((v.x - (float)hi.x) * 1024.f),
                   (_Float16)((v.y - (float)hi.y) * 1024.f),
                   (_Float16)((v.z - (float)hi.z) * 1024.f),
                   (_Float16)((v.w - (float)hi.w) * 1024.f)};
      int base = col * 72 + (kk >> 3) * 16 + (kk & 7);
      *(half4v*)&Bs[base] = hi;
      *(half4v*)&Bs[base + 8] = lo;
    }
    __syncthreads();
    half8v ah[4], al[4];
#pragma unroll
    for (int i = 0; i < 4; ++i) {
      int base = (wm * 64 + i * 16 + lr) * 72 + lk * 16;
      ah[i] = *(const half8v*)&As[base];
      al[i] = *(const half8v*)&As[base + 8];
    }
#pragma unroll
    for (int j = 0; j < 2; ++j) {
      int base = (wn * 32 + j * 16 + lr) * 72 + lk * 16;
      half8v bh = *(const half8v*)&Bs[base];
      half8v bl = *(const half8v*)&Bs[base + 8];
#pragma unroll
      for (int i = 0; i < 4; ++i) {
        a1[i][j] = mfma16(ah[i], bh, a1[i][j]);
        a2[i][j] = mfma16(ah[i], bl, a2[i][j]);
        a2[i][j] = mfma16(al[i], bh, a2[i][j]);
      }
    }
    __syncthreads();
  }
#pragma unroll
  for (int j = 0; j < 2; ++j) {
    int n = n0 + wn * 32 + j * 16 + lr;
    if (n < NV) {
#pragma unroll
      for (int i = 0; i < 4; ++i) {
        int row = wm * 64 + i * 16 + lk * 4;
#pragma unroll
        for (int r = 0; r < 4; ++r)
          out[(size_t)(row + r) * NV + n] =
              a1[i][j][r] + a2[i][j][r] * (1.f / 1024.f);
      }
    }
  }
}

extern "C" void kernel_launch(void* const* d_in, const int* in_sizes, int n_in,
                              void* d_out, int out_size, void* d_ws, size_t ws_size,
                              hipStream_t stream) {
  const int* ids = (const int*)d_in[0];
  const int* lens = (const int*)d_in[1];
  const float* emb = (const float*)d_in[2];
  const float* w_ih = (const float*)d_in[3];
  const float* w_hh = (const float*)d_in[4];
  const float* b_ih = (const float*)d_in[5];
  const float* b_hh = (const float*)d_in[6];
  float* out = (float*)d_out;

  char* ws = (char*)d_ws;
  __half* gates = (__half*)ws;                           // 78,643,200 B
  float* hfin = (float*)(ws + (size_t)B_ * T_ * G3 * sizeof(__half));
  unsigned int* whh_r =
      (unsigned int*)(ws + (size_t)B_ * T_ * G3 * sizeof(__half)
                      + (size_t)B_ * H_ * sizeof(float));   // 393,216 B
  unsigned int* wih_t = whh_r + (size_t)98304;              // 393,216 B

  pack_whh_r<<<dim3(384), dim3(256), 0, stream>>>(w_hh, whh_r);
  pack_wiht<<<dim3(384), dim3(256), 0, stream>>>(w_ih, wih_t);
  gates_mfma<<<dim3(400, 3), dim3(512), 0, stream>>>(
      ids, emb, (const __half*)wih_t, b_ih, gates);
  rec_kernel<<<dim3(B_), dim3(768), 0, stream>>>(lens, whh_r, b_hh, gates, hfin);
  logits_mfma<<<dim3((NV + 63) / 64), dim3(512), 0, stream>>>(hfin, emb, out);
}